// Round 6
// baseline (11106.033 us; speedup 1.0000x reference)
//
#include <hip/hip_runtime.h>
#include <math.h>

// Problem: B=64, T=512, I=128, H=1024, O=128; gates order i,j,f,o; relu activations.
#define Bsz 64
#define Tn  512
#define In  128
#define Hn  1024
#define KT  1152      // I + H
#define NBLK 128      // persistent blocks; each owns 8 hidden cols (x4 gates = 32 cols)

typedef __attribute__((ext_vector_type(8))) short bf16x8;   // 8 bf16 = 4 VGPRs (MFMA A/B frag)
typedef __attribute__((ext_vector_type(4))) short s16x4;
typedef __attribute__((ext_vector_type(4))) float f32x4;
typedef __attribute__((ext_vector_type(4))) int   i32x4;

// Raw buffer intrinsics. cpol 17 = SC0|SC1 on gfx950: performed at the IF/MALL
// coherence point -> cross-XCD coherent, bypasses (and never pollutes) L1/L2.
__device__ i32x4 llvm_amdgcn_raw_buffer_load_i32x4(i32x4 srsrc, int voffset, int soffset, int cpol) __asm("llvm.amdgcn.raw.buffer.load.v4i32");
__device__ void  llvm_amdgcn_raw_buffer_store_i32x4(i32x4 vdata, i32x4 srsrc, int voffset, int soffset, int cpol) __asm("llvm.amdgcn.raw.buffer.store.v4i32");
__device__ void  llvm_amdgcn_raw_buffer_store_i16(short vdata, i32x4 srsrc, int voffset, int soffset, int cpol) __asm("llvm.amdgcn.raw.buffer.store.i16");

union B128 { i32x4 i; bf16x8 h; };

__device__ __forceinline__ i32x4 make_srd(const void* p, int bytes) {
  i32x4 r;
  r.x = (int)(unsigned)(unsigned long long)p;
  r.y = (int)((unsigned long long)p >> 32);   // stride = 0
  r.z = bytes;                                // num_records (bytes when stride==0)
  r.w = 0x00020000;                           // raw dword access
  return r;
}

// LDS-only block barrier: does NOT drain vmcnt, so sc1 h-stores keep draining
// to the MALL in the background instead of serializing into every step.
__device__ __forceinline__ void bar_lds() {
  asm volatile("s_waitcnt lgkmcnt(0)\n\ts_barrier" ::: "memory");
}

__device__ __forceinline__ unsigned short f2bf(float f) {
  union { float f; unsigned u; } x; x.f = f;
  unsigned r = x.u + 0x7FFFu + ((x.u >> 16) & 1u);   // RNE
  return (unsigned short)(r >> 16);
}
__device__ __forceinline__ float sigmoidf_(float x) { return 1.0f / (1.0f + __expf(-x)); }

// ---------------- prep: X (fp32) -> Xb (bf16), elementwise ----------------
__global__ __launch_bounds__(256) void cast_x_kernel(const float* __restrict__ in,
                                                     unsigned short* __restrict__ out) {
  int i = blockIdx.x * 256 + threadIdx.x;
  f32x4 v = ((const f32x4*)in)[i];
  s16x4 o;
  o.x = (short)f2bf(v.x); o.y = (short)f2bf(v.y);
  o.z = (short)f2bf(v.z); o.w = (short)f2bf(v.w);
  ((s16x4*)out)[i] = o;
}

// ---- prep: poison hs at the COHERENCE POINT (sc1 stores reach the MALL, so
// consumer sc1 polls can never see stale sign-clear data from a prior replay).
// 0xAAAA has the bf16 sign bit set; real h = bf16(o*relu(c)) >= 0 -> sign clear.
__global__ __launch_bounds__(256) void poison_hs_kernel(unsigned short* __restrict__ hs) {
  const i32x4 srd = make_srd(hs, Tn * Bsz * Hn * 2);
  i32x4 v; v.x = v.y = v.z = v.w = (int)0xAAAAAAAAu;
  int i = blockIdx.x * 256 + threadIdx.x;     // 16B chunks: 67108864/16 = 4194304
  llvm_amdgcn_raw_buffer_store_i32x4(v, srd, i * 16, 0, 17);
}

// -------- prep: transpose+cast fp32 [R][C] -> bf16 [C][ldo] (64x64 LDS tiles) --------
__global__ __launch_bounds__(256) void transpose_cast_kernel(const float* __restrict__ in,
                                                             unsigned short* __restrict__ out,
                                                             int R, int C, int ldo, int tilesR) {
  __shared__ unsigned short tile[64][73];
  int br = blockIdx.x % tilesR, bc = blockIdx.x / tilesR;
  int r0 = br << 6, c0 = bc << 6;
  for (int e = threadIdx.x; e < 4096; e += 256) {
    int r = e >> 6, c = e & 63;
    tile[r][c] = f2bf(in[(size_t)(r0 + r) * C + (c0 + c)]);
  }
  __syncthreads();
  for (int e = threadIdx.x; e < 4096; e += 256) {
    int c = e >> 6, r = e & 63;
    out[(size_t)(c0 + c) * ldo + (r0 + r)] = tile[r][c];
  }
}

// ---------------- persistent LSTM recurrence: pure dataflow ----------------
// Block blk owns hidden cols j in [blk*8, blk*8+8), gate cols {j, H+j, 2H+j, 3H+j}.
// 8 waves = (2 batch-halves mh) x (4 K-quarters kq); B-frags register-resident.
// NO grid sync at all: consumers poll the h segments themselves with sc1 loads
// until every short is sign-clear (written). (block,t) dependencies form a DAG
// (step t reads only step t-1) -> deadlock-free; blocks free-run and pipeline.
__global__ __launch_bounds__(512, 1) void lstm_kernel(
    const unsigned short* __restrict__ Xb,    // [64][512][128] bf16
    const unsigned short* __restrict__ WkT,   // [4096][1152]  bf16 (col-major-in-k)
    const float* __restrict__ bias,           // [4096]
    unsigned short* __restrict__ hs)          // [512][64][1024] bf16 (output history)
{
  __shared__ float Z4[4][64][36];             // per-kq partials [kq][batch][32 cols], ld 36
  const int tid = threadIdx.x;
  const int blk = blockIdx.x;
  const int w   = tid >> 6;
  const int mh  = w & 1;                      // batch half (32 rows)
  const int kq  = w >> 1;                     // K quarter (288 of 1152)
  const int l   = tid & 63, q = l >> 4, n16 = l & 15;

  const i32x4 hsrd = make_srd(hs, Tn * Bsz * Hn * 2);

  // ---- load register-resident B fragments (once) ----
  bf16x8 Bf[2][9];
#pragma unroll
  for (int nt = 0; nt < 2; ++nt) {
    int cl   = nt * 16 + n16;                                  // local col 0..31
    int gcol = (cl >> 3) * Hn + blk * 8 + (cl & 7);            // gate*1024 + j
    const unsigned short* bp = WkT + (size_t)gcol * KT + kq * 288 + q * 8;
#pragma unroll
    for (int ks = 0; ks < 9; ++ks)
      Bf[nt][ks] = *(const bf16x8*)(bp + ks * 32);
  }

  // ---- epilogue constants: thread = (batch eb, col ej) ----
  const int eb = tid >> 3, ej = tid & 7;
  const float bi  = bias[           blk * 8 + ej];
  const float bg  = bias[    Hn   + blk * 8 + ej];
  const float bfg = bias[2 * Hn   + blk * 8 + ej] + 1.0f;      // TF forget bias
  const float bo  = bias[3 * Hn   + blk * 8 + ej];
  const int   hst_off = (eb * Hn + blk * 8 + ej) * 2;          // per-thread h store (byte, sans t)
  float cst = 0.0f;                                            // cell state, persistent in VGPR

  const int b0 = mh * 32 + n16;                                // A rows (two 16-batch tiles)
  const int b1 = b0 + 16;
  const int firstks = (kq == 0) ? 4 : 0;                       // ks range reading h

  for (int t = 0; t < Tn; ++t) {
    f32x4 a00 = {0,0,0,0}, a01 = {0,0,0,0}, a10 = {0,0,0,0}, a11 = {0,0,0,0};
    B128 H0[9], H1[9];

    if (t > 0) {
      // x-part frags (kq0, ks<4): plain loads, no dependency on the recurrence
      if (kq == 0) {
#pragma unroll
        for (int ks = 0; ks < 4; ++ks) {
          H0[ks].h = *(const bf16x8*)(Xb + ((size_t)b0 * Tn + t) * In + ks * 32 + q * 8);
          H1[ks].h = *(const bf16x8*)(Xb + ((size_t)b1 * Tn + t) * In + ks * 32 + q * 8);
        }
      }
      // ---- data-embedded sync: sc1-poll h segments until all shorts sign-clear ----
      const int hb = (t - 1) << 17;                            // (t-1)*64*1024*2
      for (;;) {
#pragma unroll
        for (int ks = firstks; ks < 9; ++ks) {
          int kh2 = (kq * 288 + ks * 32 - 128 + q * 8) * 2;    // h col byte offset
          H0[ks].i = llvm_amdgcn_raw_buffer_load_i32x4(hsrd, hb + (b0 << 11) + kh2, 0, 17);
          H1[ks].i = llvm_amdgcn_raw_buffer_load_i32x4(hsrd, hb + (b1 << 11) + kh2, 0, 17);
        }
        int v = 0;
#pragma unroll
        for (int ks = firstks; ks < 9; ++ks) {
          v |= H0[ks].i.x | H0[ks].i.y | H0[ks].i.z | H0[ks].i.w;
          v |= H1[ks].i.x | H1[ks].i.y | H1[ks].i.z | H1[ks].i.w;
        }
        bool ok = ((v & 0x80008000u) == 0);                    // all 8+8 shorts written
        if (__ballot(ok) == ~0ull) break;
        __builtin_amdgcn_s_sleep(1);
        asm volatile("" ::: "memory");                         // force reload next round
      }
#pragma unroll
      for (int ks = 0; ks < 9; ++ks) {
        a00 = __builtin_amdgcn_mfma_f32_16x16x32_bf16(H0[ks].h, Bf[0][ks], a00, 0, 0, 0);
        a01 = __builtin_amdgcn_mfma_f32_16x16x32_bf16(H0[ks].h, Bf[1][ks], a01, 0, 0, 0);
        a10 = __builtin_amdgcn_mfma_f32_16x16x32_bf16(H1[ks].h, Bf[0][ks], a10, 0, 0, 0);
        a11 = __builtin_amdgcn_mfma_f32_16x16x32_bf16(H1[ks].h, Bf[1][ks], a11, 0, 0, 0);
      }
    } else if (kq == 0) {                                      // t==0: h==0, x-part only
#pragma unroll
      for (int ks = 0; ks < 4; ++ks) {
        bf16x8 A0 = *(const bf16x8*)(Xb + ((size_t)b0 * Tn) * In + ks * 32 + q * 8);
        bf16x8 A1 = *(const bf16x8*)(Xb + ((size_t)b1 * Tn) * In + ks * 32 + q * 8);
        a00 = __builtin_amdgcn_mfma_f32_16x16x32_bf16(A0, Bf[0][ks], a00, 0, 0, 0);
        a01 = __builtin_amdgcn_mfma_f32_16x16x32_bf16(A0, Bf[1][ks], a01, 0, 0, 0);
        a10 = __builtin_amdgcn_mfma_f32_16x16x32_bf16(A1, Bf[0][ks], a10, 0, 0, 0);
        a11 = __builtin_amdgcn_mfma_f32_16x16x32_bf16(A1, Bf[1][ks], a11, 0, 0, 0);
      }
    }

    // ---- write per-kq partials (no atomics) ----
#pragma unroll
    for (int r = 0; r < 4; ++r) {
      int row = mh * 32 + q * 4 + r;
      Z4[kq][row     ][     n16] = a00[r];
      Z4[kq][row     ][16 + n16] = a01[r];
      Z4[kq][row + 16][     n16] = a10[r];
      Z4[kq][row + 16][16 + n16] = a11[r];
    }
    bar_lds();                                 // LDS-only: h-stores keep draining

    // ---- gates + cell update: one (batch, col) per thread; sum 4 kq partials ----
    float zi = bi, zg = bg, zf = bfg, zo = bo;
#pragma unroll
    for (int k2 = 0; k2 < 4; ++k2) {
      zi += Z4[k2][eb][     ej];
      zg += Z4[k2][eb][ 8 + ej];
      zf += Z4[k2][eb][16 + ej];
      zo += Z4[k2][eb][24 + ej];
    }
    float ig = sigmoidf_(zi);
    float g  = fmaxf(zg, 0.0f);
    float ff = sigmoidf_(zf);
    float oo = sigmoidf_(zo);
    cst = ff * cst + ig * g;
    float hn = oo * fmaxf(cst, 0.0f);          // >= 0 -> bf16 sign bit 0 (the "valid" tag)
    llvm_amdgcn_raw_buffer_store_i16((short)f2bf(hn), hsrd,
                                     t * (Bsz * Hn * 2) + hst_off, 0, 17);
    bar_lds();                                 // Z4 reads done before next iter's writes
  }
}

// ---------------- dense epilogue: out[b,t,:] = hs_row @ Wd + bd ----------------
__global__ __launch_bounds__(256) void dense_kernel(
    const unsigned short* __restrict__ hs,    // [32768][1024] bf16, row = t*64+b
    const unsigned short* __restrict__ WdT,   // [128][1024] bf16
    const float* __restrict__ bd,             // [128]
    float* __restrict__ out)                  // [64][512][128] fp32
{
  const int tid = threadIdx.x;
  const int w = tid >> 6, l = tid & 63, q = l >> 4, n16 = l & 15;
  const int R0 = blockIdx.x * 64 + w * 16;
  f32x4 acc[8];
#pragma unroll
  for (int i = 0; i < 8; ++i) acc[i] = (f32x4){0, 0, 0, 0};
  const unsigned short* arow = hs + (size_t)(R0 + n16) * Hn + q * 8;
#pragma unroll 4
  for (int ks = 0; ks < 32; ++ks) {
    bf16x8 A = *(const bf16x8*)(arow + ks * 32);
#pragma unroll
    for (int nt = 0; nt < 8; ++nt) {
      bf16x8 Bf = *(const bf16x8*)(WdT + (size_t)(nt * 16 + n16) * Hn + ks * 32 + q * 8);
      acc[nt] = __builtin_amdgcn_mfma_f32_16x16x32_bf16(A, Bf, acc[nt], 0, 0, 0);
    }
  }
#pragma unroll
  for (int nt = 0; nt < 8; ++nt) {
    int col = nt * 16 + n16;
    float bdv = bd[col];
#pragma unroll
    for (int r = 0; r < 4; ++r) {
      int R = R0 + q * 4 + r;
      int b = R & 63, t = R >> 6;
      out[((size_t)b * Tn + t) * 128 + col] = acc[nt][r] + bdv;
    }
  }
}

// ---------------- launcher ----------------
extern "C" void kernel_launch(void* const* d_in, const int* in_sizes, int n_in,
                              void* d_out, int out_size, void* d_ws, size_t ws_size,
                              hipStream_t stream) {
  const float* X    = (const float*)d_in[0];   // [64][512][128]
  const float* Wk   = (const float*)d_in[1];   // [1152][4096]
  const float* bias = (const float*)d_in[2];   // [4096]
  const float* Wd   = (const float*)d_in[3];   // [1024][128]
  const float* bd   = (const float*)d_in[4];   // [128]
  float* out = (float*)d_out;

  // ws layout (bytes):
  char* ws = (char*)d_ws;
  unsigned short* Xb  = (unsigned short*)(ws);              //  8,388,608
  unsigned short* WkT = (unsigned short*)(ws + 8388608);    //  9,437,184
  unsigned short* WdT = (unsigned short*)(ws + 17825792);   //    262,144
  unsigned short* hs  = (unsigned short*)(ws + 18087936);   // 67,108,864

  cast_x_kernel<<<4096, 256, 0, stream>>>(X, Xb);
  poison_hs_kernel<<<16384, 256, 0, stream>>>(hs);
  transpose_cast_kernel<<<1152, 256, 0, stream>>>(Wk, WkT, 1152, 4096, 1152, 18);
  transpose_cast_kernel<<<32, 256, 0, stream>>>(Wd, WdT, 1024, 128, 1024, 16);
  lstm_kernel<<<NBLK, 512, 0, stream>>>(Xb, WkT, bias, hs);
  dense_kernel<<<512, 256, 0, stream>>>(hs, WdT, bd, out);
}

// Round 7
// 3914.345 us; speedup vs baseline: 2.8373x; 2.8373x over previous
//
#include <hip/hip_runtime.h>
#include <math.h>

// Problem: B=64, T=512, I=128, H=1024, O=128; gates order i,j,f,o; relu activations.
#define Bsz 64
#define Tn  512
#define In  128
#define Hn  1024
#define KT  1152      // I + H
#define NBLK 128      // persistent blocks; each owns 8 hidden cols (x4 gates = 32 cols)

typedef __attribute__((ext_vector_type(8))) short bf16x8;   // 8 bf16 = 4 VGPRs (MFMA A/B frag)
typedef __attribute__((ext_vector_type(4))) short s16x4;
typedef __attribute__((ext_vector_type(4))) float f32x4;
typedef __attribute__((ext_vector_type(4))) int   i32x4;

// Raw buffer intrinsics. cpol 17 = SC0|SC1 on gfx950: system-scope, performed at
// the coherence point. R6 lesson: NEVER use for bulk data (HBM sector traffic);
// use ONLY for the block's 1KB h-slice store (16B/lane, one wave) + control words.
__device__ void llvm_amdgcn_raw_buffer_store_i32x4(i32x4 vdata, i32x4 srsrc, int voffset, int soffset, int cpol) __asm("llvm.amdgcn.raw.buffer.store.v4i32");

union B128 { i32x4 i; bf16x8 h; };

__device__ __forceinline__ i32x4 make_srd(const void* p, int bytes) {
  i32x4 r;
  r.x = (int)(unsigned)(unsigned long long)p;
  r.y = (int)((unsigned long long)p >> 32);   // stride = 0
  r.z = bytes;                                // num_records (bytes when stride==0)
  r.w = 0x00020000;                           // raw dword access
  return r;
}

// LDS-only block barrier: does NOT drain vmcnt, so pending global ops (h store
// acks, x prefetches) keep flying while waves sync on LDS state.
__device__ __forceinline__ void bar_lds() {
  asm volatile("s_waitcnt lgkmcnt(0)\n\ts_barrier" ::: "memory");
}

__device__ __forceinline__ unsigned short f2bf(float f) {
  union { float f; unsigned u; } x; x.f = f;
  unsigned r = x.u + 0x7FFFu + ((x.u >> 16) & 1u);   // RNE
  return (unsigned short)(r >> 16);
}
__device__ __forceinline__ float sigmoidf_(float x) { return 1.0f / (1.0f + __expf(-x)); }

// ---------------- prep: X (fp32) -> Xb (bf16), elementwise ----------------
__global__ __launch_bounds__(256) void cast_x_kernel(const float* __restrict__ in,
                                                     unsigned short* __restrict__ out) {
  int i = blockIdx.x * 256 + threadIdx.x;
  f32x4 v = ((const f32x4*)in)[i];
  s16x4 o;
  o.x = (short)f2bf(v.x); o.y = (short)f2bf(v.y);
  o.z = (short)f2bf(v.z); o.w = (short)f2bf(v.w);
  ((s16x4*)out)[i] = o;
}

// -------- prep: transpose+cast fp32 [R][C] -> bf16 [C][ldo] (64x64 LDS tiles) --------
__global__ __launch_bounds__(256) void transpose_cast_kernel(const float* __restrict__ in,
                                                             unsigned short* __restrict__ out,
                                                             int R, int C, int ldo, int tilesR) {
  __shared__ unsigned short tile[64][73];
  int br = blockIdx.x % tilesR, bc = blockIdx.x / tilesR;
  int r0 = br << 6, c0 = bc << 6;
  for (int e = threadIdx.x; e < 4096; e += 256) {
    int r = e >> 6, c = e & 63;
    tile[r][c] = f2bf(in[(size_t)(r0 + r) * C + (c0 + c)]);
  }
  __syncthreads();
  for (int e = threadIdx.x; e < 4096; e += 256) {
    int c = e >> 6, r = e & 63;
    out[(size_t)(c0 + c) * ldo + (r0 + r)] = tile[r][c];
  }
}

// ---------------- persistent LSTM recurrence ----------------
// Block blk owns hidden cols j in [blk*8, blk*8+8), gate cols {j, H+j, 2H+j, 3H+j}.
// 8 waves = (2 batch-halves mh) x (4 K-quarters kq); B-frags register-resident.
// Sync: per-block flags (packed, 4 cache lines), producer = plain agent atomic
// store t+1 (NO RMW, no group indirection); consumer waves poll exactly their
// true producer blocks (one lane each + ballot) with s_sleep backoff.
// h data plane: LDS-gathered, wave0-only 16B/lane sc1 store (coherence point),
// wave0-only vmcnt drain before the flag; consumer loads PLAIN (L2-cached,
// virgin t-lines -> coherent; proven R3/R5).
__global__ __launch_bounds__(512, 1) void lstm_kernel(
    const unsigned short* __restrict__ Xb,    // [64][512][128] bf16
    const unsigned short* __restrict__ WkT,   // [4096][1152]  bf16 (col-major-in-k)
    const float* __restrict__ bias,           // [4096]
    unsigned short* __restrict__ hs,          // [512][64][1024] bf16 (output history)
    unsigned* __restrict__ S)                 // flags[128] (zeroed)
{
  __shared__ float Z4[4][64][36];             // per-kq partials [kq][batch][32 cols], ld 36
  __shared__ unsigned short hstage[64][8];    // block's h(t) slice [batch][8 cols]
  const int tid = threadIdx.x;
  const int blk = blockIdx.x;
  const int w   = tid >> 6;
  const int mh  = w & 1;                      // batch half (32 rows)
  const int kq  = w >> 1;                     // K quarter (288 of 1152)
  const int l   = tid & 63, q = l >> 4, n16 = l & 15;

  const i32x4 hsrd = make_srd(hs, Tn * Bsz * Hn * 2);

  // ---- load register-resident B fragments (once) ----
  bf16x8 Bf[2][9];
#pragma unroll
  for (int nt = 0; nt < 2; ++nt) {
    int cl   = nt * 16 + n16;                                  // local col 0..31
    int gcol = (cl >> 3) * Hn + blk * 8 + (cl & 7);            // gate*1024 + j
    const unsigned short* bp = WkT + (size_t)gcol * KT + kq * 288 + q * 8;
#pragma unroll
    for (int ks = 0; ks < 9; ++ks)
      Bf[nt][ks] = *(const bf16x8*)(bp + ks * 32);
  }

  // ---- epilogue constants: thread = (batch eb, col ej) ----
  const int eb = tid >> 3, ej = tid & 7;
  const float bi  = bias[           blk * 8 + ej];
  const float bg  = bias[    Hn   + blk * 8 + ej];
  const float bfg = bias[2 * Hn   + blk * 8 + ej] + 1.0f;      // TF forget bias
  const float bo  = bias[3 * Hn   + blk * 8 + ej];
  float cst = 0.0f;                                            // cell state, persistent in VGPR

  const int b0 = mh * 32 + n16;                                // A rows (two 16-batch tiles)
  const int b1 = b0 + 16;

  // ---- per-wave exact producer-block poll set (packed flags, 1 word/lane) ----
  // wave kq h-cols: kq0 [0,160) kq1 [160,448) kq2 [448,736) kq3 [736,1024)
  // producer blocks: kq0 0..19 | kq1 20..55 | kq2 56..91 | kq3 92..127
  const int pfirst = (kq == 0) ? 0 : (kq == 1) ? 20 : (kq == 2) ? 56 : 92;
  const int pcnt   = (kq == 0) ? 20 : 36;
  const bool mine  = (l < pcnt);
  const int  pidx  = pfirst + (mine ? l : 0);

  for (int t = 0; t < Tn; ++t) {
    f32x4 a00 = {0,0,0,0}, a01 = {0,0,0,0}, a10 = {0,0,0,0}, a11 = {0,0,0,0};

    if (t > 0) {
      // x-part A-frags don't depend on flags: prefetch before polling (kq0 only)
      bf16x8 X0[4], X1[4];
      if (kq == 0) {
#pragma unroll
        for (int ks = 0; ks < 4; ++ks) {
          X0[ks] = *(const bf16x8*)(Xb + ((size_t)b0 * Tn + t) * In + ks * 32 + q * 8);
          X1[ks] = *(const bf16x8*)(Xb + ((size_t)b1 * Tn + t) * In + ks * 32 + q * 8);
        }
      }
      // wave-local wait: this wave's true producers must have finished step t-1
      for (;;) {
        unsigned f = mine ? __hip_atomic_load(&S[pidx], __ATOMIC_RELAXED,
                                              __HIP_MEMORY_SCOPE_AGENT)
                          : 0xFFFFFFFFu;
        if (__ballot(f >= (unsigned)t) == ~0ull) break;
        __builtin_amdgcn_s_sleep(1);
      }
      const unsigned short* hrow = hs + (size_t)(t - 1) * (Bsz * Hn);
#pragma unroll
      for (int ks = 0; ks < 9; ++ks) {
        bf16x8 A0, A1;
        if (kq == 0 && ks < 4) {
          A0 = X0[ks]; A1 = X1[ks];
        } else {
          int kh = kq * 288 + ks * 32 - 128 + q * 8;           // h col
          A0 = *(const bf16x8*)(hrow + (size_t)b0 * Hn + kh);
          A1 = *(const bf16x8*)(hrow + (size_t)b1 * Hn + kh);
        }
        a00 = __builtin_amdgcn_mfma_f32_16x16x32_bf16(A0, Bf[0][ks], a00, 0, 0, 0);
        a01 = __builtin_amdgcn_mfma_f32_16x16x32_bf16(A0, Bf[1][ks], a01, 0, 0, 0);
        a10 = __builtin_amdgcn_mfma_f32_16x16x32_bf16(A1, Bf[0][ks], a10, 0, 0, 0);
        a11 = __builtin_amdgcn_mfma_f32_16x16x32_bf16(A1, Bf[1][ks], a11, 0, 0, 0);
      }
    } else if (kq == 0) {                                      // t==0: h==0, x-part only
#pragma unroll
      for (int ks = 0; ks < 4; ++ks) {
        bf16x8 A0 = *(const bf16x8*)(Xb + ((size_t)b0 * Tn) * In + ks * 32 + q * 8);
        bf16x8 A1 = *(const bf16x8*)(Xb + ((size_t)b1 * Tn) * In + ks * 32 + q * 8);
        a00 = __builtin_amdgcn_mfma_f32_16x16x32_bf16(A0, Bf[0][ks], a00, 0, 0, 0);
        a01 = __builtin_amdgcn_mfma_f32_16x16x32_bf16(A0, Bf[1][ks], a01, 0, 0, 0);
        a10 = __builtin_amdgcn_mfma_f32_16x16x32_bf16(A1, Bf[0][ks], a10, 0, 0, 0);
        a11 = __builtin_amdgcn_mfma_f32_16x16x32_bf16(A1, Bf[1][ks], a11, 0, 0, 0);
      }
    }

    // ---- write per-kq partials (no atomics) ----
#pragma unroll
    for (int r = 0; r < 4; ++r) {
      int row = mh * 32 + q * 4 + r;
      Z4[kq][row     ][     n16] = a00[r];
      Z4[kq][row     ][16 + n16] = a01[r];
      Z4[kq][row + 16][     n16] = a10[r];
      Z4[kq][row + 16][16 + n16] = a11[r];
    }
    bar_lds();                                 // (A) partials visible to gate phase

    // ---- gates + cell update: one (batch, col) per thread; sum 4 kq partials ----
    float zi = bi, zg = bg, zf = bfg, zo = bo;
#pragma unroll
    for (int k2 = 0; k2 < 4; ++k2) {
      zi += Z4[k2][eb][     ej];
      zg += Z4[k2][eb][ 8 + ej];
      zf += Z4[k2][eb][16 + ej];
      zo += Z4[k2][eb][24 + ej];
    }
    float ig = sigmoidf_(zi);
    float g  = fmaxf(zg, 0.0f);
    float ff = sigmoidf_(zf);
    float oo = sigmoidf_(zo);
    cst = ff * cst + ig * g;
    float hn = oo * fmaxf(cst, 0.0f);
    hstage[eb][ej] = f2bf(hn);                 // stage block's h(t) slice in LDS
    bar_lds();                                 // (B) hstage complete; Z4 reads done

    // ---- wave0 only: vectorized coherent h store + flag; others run ahead ----
    if (w == 0) {
      B128 v; v.h = *(const bf16x8*)&hstage[l][0];   // lane = batch row, 16B
      llvm_amdgcn_raw_buffer_store_i32x4(v.i, hsrd,
          t * (Bsz * Hn * 2) + l * (Hn * 2) + blk * 16, 0, 17);
      if (t < Tn - 1) {
        asm volatile("s_waitcnt vmcnt(0)" ::: "memory");  // MALL ack of all 64 lanes
        if (tid == 0)
          __hip_atomic_store(&S[blk], (unsigned)(t + 1),
                             __ATOMIC_RELAXED, __HIP_MEMORY_SCOPE_AGENT);
      }
    }
    // next iteration's Z4/hstage writes are ordered after (B) for all waves;
    // wave0's hstage read above precedes its own next bar (A) -> no race.
  }
}

// ---------------- dense epilogue: out[b,t,:] = hs_row @ Wd + bd ----------------
__global__ __launch_bounds__(256) void dense_kernel(
    const unsigned short* __restrict__ hs,    // [32768][1024] bf16, row = t*64+b
    const unsigned short* __restrict__ WdT,   // [128][1024] bf16
    const float* __restrict__ bd,             // [128]
    float* __restrict__ out)                  // [64][512][128] fp32
{
  const int tid = threadIdx.x;
  const int w = tid >> 6, l = tid & 63, q = l >> 4, n16 = l & 15;
  const int R0 = blockIdx.x * 64 + w * 16;
  f32x4 acc[8];
#pragma unroll
  for (int i = 0; i < 8; ++i) acc[i] = (f32x4){0, 0, 0, 0};
  const unsigned short* arow = hs + (size_t)(R0 + n16) * Hn + q * 8;
#pragma unroll 4
  for (int ks = 0; ks < 32; ++ks) {
    bf16x8 A = *(const bf16x8*)(arow + ks * 32);
#pragma unroll
    for (int nt = 0; nt < 8; ++nt) {
      bf16x8 Bf = *(const bf16x8*)(WdT + (size_t)(nt * 16 + n16) * Hn + ks * 32 + q * 8);
      acc[nt] = __builtin_amdgcn_mfma_f32_16x16x32_bf16(A, Bf, acc[nt], 0, 0, 0);
    }
  }
#pragma unroll
  for (int nt = 0; nt < 8; ++nt) {
    int col = nt * 16 + n16;
    float bdv = bd[col];
#pragma unroll
    for (int r = 0; r < 4; ++r) {
      int R = R0 + q * 4 + r;
      int b = R & 63, t = R >> 6;
      out[((size_t)b * Tn + t) * 128 + col] = acc[nt][r] + bdv;
    }
  }
}

// ---------------- launcher ----------------
extern "C" void kernel_launch(void* const* d_in, const int* in_sizes, int n_in,
                              void* d_out, int out_size, void* d_ws, size_t ws_size,
                              hipStream_t stream) {
  const float* X    = (const float*)d_in[0];   // [64][512][128]
  const float* Wk   = (const float*)d_in[1];   // [1152][4096]
  const float* bias = (const float*)d_in[2];   // [4096]
  const float* Wd   = (const float*)d_in[3];   // [1024][128]
  const float* bd   = (const float*)d_in[4];   // [128]
  float* out = (float*)d_out;

  // ws layout (bytes):
  char* ws = (char*)d_ws;
  unsigned short* Xb  = (unsigned short*)(ws);              //  8,388,608
  unsigned short* WkT = (unsigned short*)(ws + 8388608);    //  9,437,184
  unsigned short* WdT = (unsigned short*)(ws + 17825792);   //    262,144
  unsigned short* hs  = (unsigned short*)(ws + 18087936);   // 67,108,864
  unsigned*       syn = (unsigned*)      (ws + 85196800);   //        512 (flags[128])

  hipMemsetAsync(syn, 0, 512, stream);
  cast_x_kernel<<<4096, 256, 0, stream>>>(X, Xb);
  transpose_cast_kernel<<<1152, 256, 0, stream>>>(Wk, WkT, 1152, 4096, 1152, 18);
  transpose_cast_kernel<<<32, 256, 0, stream>>>(Wd, WdT, 1024, 128, 1024, 16);
  lstm_kernel<<<NBLK, 512, 0, stream>>>(Xb, WkT, bias, hs, syn);
  dense_kernel<<<512, 256, 0, stream>>>(hs, WdT, bd, out);
}